// Round 3
// baseline (1177.153 us; speedup 1.0000x reference)
//
#include <hip/hip_runtime.h>
#include <math.h>

#define N_NODES 50000
#define N_EDGES 800000
#define EPS 1e-5f

typedef unsigned short u16;
typedef __attribute__((ext_vector_type(8))) u16 u16x8;
typedef __attribute__((ext_vector_type(8))) short bf16x8;
typedef __attribute__((ext_vector_type(4))) float f32x4;

__device__ __forceinline__ u16 f2bf(float x) {
  unsigned u = __float_as_uint(x);
  return (u16)((u + 0x7FFFu + ((u >> 16) & 1u)) >> 16);
}
__device__ __forceinline__ float bf2f(u16 b) {
  return __uint_as_float(((unsigned)b) << 16);
}

// ============================ CSR build ============================
__global__ void count_kernel(const int* __restrict__ dst, int* __restrict__ cnt, int e_total) {
  int e = blockIdx.x * 256 + threadIdx.x;
  if (e < e_total) atomicAdd(&cnt[dst[e]], 1);
}

__global__ void scan_kernel(const int* __restrict__ cnt, int* __restrict__ offs,
                            int* __restrict__ cursor, int n) {
  __shared__ int buf[1024];
  int t = threadIdx.x;
  int chunk = (n + 1023) >> 10;
  int lo = t * chunk, hi = min(lo + chunk, n);
  int s = 0;
  for (int i = lo; i < hi; ++i) s += cnt[i];
  buf[t] = s;
  __syncthreads();
  for (int st = 1; st < 1024; st <<= 1) {
    int v = (t >= st) ? buf[t - st] : 0;
    __syncthreads();
    buf[t] += v;
    __syncthreads();
  }
  int run = (t == 0) ? 0 : buf[t - 1];
  for (int i = lo; i < hi; ++i) {
    int c = cnt[i];
    offs[i] = run; cursor[i] = run;
    run += c;
  }
  if (lo < n && hi == n) offs[n] = run;
}

__global__ void scatter_kernel(const int* __restrict__ src, const int* __restrict__ dst,
                               int* __restrict__ cursor, int* __restrict__ ssrc, int e_total) {
  int e = blockIdx.x * 256 + threadIdx.x;
  if (e < e_total) {
    int p = atomicAdd(&cursor[dst[e]], 1);
    ssrc[p] = src[e];
  }
}

// ============================ weight transpose + split ============================
// W[K][M] fp32 -> WT_h/WT_l [M][K] bf16 bits
__global__ void wsplit_kernel(const float* __restrict__ W, u16* __restrict__ outH,
                              u16* __restrict__ outL, int K, int M) {
  int e = blockIdx.x * 256 + threadIdx.x;
  if (e >= K * M) return;
  int n = e % M, k = e / M;
  float a = W[e];
  u16 hb = f2bf(a);
  outH[(size_t)n * K + k] = hb;
  outL[(size_t)n * K + k] = f2bf(a - bf2f(hb));
}

// ============================ LayerNorm ============================
__device__ __forceinline__ float wave_sum(float v) {
#pragma unroll
  for (int m = 32; m > 0; m >>= 1) v += __shfl_xor(v, m, 64);
  return v;
}

// out = LN(LN(h, w1, b1), w2, b2), emitted as bf16 hi/lo split
__global__ __launch_bounds__(256) void ln2_kernel(
    const float* __restrict__ h,
    const float* __restrict__ w1, const float* __restrict__ b1,
    const float* __restrict__ w2, const float* __restrict__ b2,
    u16* __restrict__ s_hi, u16* __restrict__ s_lo, int n) {
  int lane = threadIdx.x & 63;
  int row = blockIdx.x * 4 + (threadIdx.x >> 6);
  if (row >= n) return;
  float2 v = ((const float2*)(h + (size_t)row * 128))[lane];
  float s = wave_sum(v.x + v.y);
  float q = wave_sum(v.x * v.x + v.y * v.y);
  float mean = s * (1.0f / 128.0f);
  float var = q * (1.0f / 128.0f) - mean * mean;
  float rs = 1.0f / sqrtf(var + EPS);
  float2 wv = ((const float2*)w1)[lane];
  float2 bv = ((const float2*)b1)[lane];
  float x0 = (v.x - mean) * rs * wv.x + bv.x;
  float x1 = (v.y - mean) * rs * wv.y + bv.y;
  float s2 = wave_sum(x0 + x1);
  float q2 = wave_sum(x0 * x0 + x1 * x1);
  float mean2 = s2 * (1.0f / 128.0f);
  float var2 = q2 * (1.0f / 128.0f) - mean2 * mean2;
  float rs2 = 1.0f / sqrtf(var2 + EPS);
  float2 wv2 = ((const float2*)w2)[lane];
  float2 bv2 = ((const float2*)b2)[lane];
  float o0 = (x0 - mean2) * rs2 * wv2.x + bv2.x;
  float o1 = (x1 - mean2) * rs2 * wv2.y + bv2.y;
  u16 h0 = f2bf(o0), h1 = f2bf(o1);
  u16 l0 = f2bf(o0 - bf2f(h0)), l1 = f2bf(o1 - bf2f(h1));
  ((unsigned*)s_hi)[(size_t)row * 64 + lane] = (unsigned)h0 | ((unsigned)h1 << 16);
  ((unsigned*)s_lo)[(size_t)row * 64 + lane] = (unsigned)l0 | ((unsigned)l1 << 16);
}

__global__ __launch_bounds__(256) void ln1_kernel(
    const float* __restrict__ h,
    const float* __restrict__ w1, const float* __restrict__ b1,
    u16* __restrict__ s_hi, u16* __restrict__ s_lo, int n) {
  int lane = threadIdx.x & 63;
  int row = blockIdx.x * 4 + (threadIdx.x >> 6);
  if (row >= n) return;
  float2 v = ((const float2*)(h + (size_t)row * 128))[lane];
  float s = wave_sum(v.x + v.y);
  float q = wave_sum(v.x * v.x + v.y * v.y);
  float mean = s * (1.0f / 128.0f);
  float var = q * (1.0f / 128.0f) - mean * mean;
  float rs = 1.0f / sqrtf(var + EPS);
  float2 wv = ((const float2*)w1)[lane];
  float2 bv = ((const float2*)b1)[lane];
  float o0 = (v.x - mean) * rs * wv.x + bv.x;
  float o1 = (v.y - mean) * rs * wv.y + bv.y;
  u16 h0 = f2bf(o0), h1 = f2bf(o1);
  u16 l0 = f2bf(o0 - bf2f(h0)), l1 = f2bf(o1 - bf2f(h1));
  ((unsigned*)s_hi)[(size_t)row * 64 + lane] = (unsigned)h0 | ((unsigned)h1 << 16);
  ((unsigned*)s_lo)[(size_t)row * 64 + lane] = (unsigned)l0 | ((unsigned)l1 << 16);
}

// ============================ Graph attention ============================
// One wave per dst node; lane owns channels (2l, 2l+1). qv[N][256] interleaved:
// q_c at 4*(c>>1)+(c&1), v_c at 4*(c>>1)+2+(c&1)  ->  one float4/lane/edge.
__global__ __launch_bounds__(256) void attn_kernel(
    const float* __restrict__ qv, const float* __restrict__ kbuf,
    const int* __restrict__ offs, const int* __restrict__ ssrc,
    float* __restrict__ rst, int n) {
  int lane = threadIdx.x & 63;
  int node = blockIdx.x * 4 + (threadIdx.x >> 6);
  if (node >= n) return;
  const float SCALE = 0.08838834764831845f;  // 128^-0.5
  float2 kc = ((const float2*)(kbuf + (size_t)node * 128))[lane];
  kc.x *= SCALE; kc.y *= SCALE;
  int e0 = offs[node], e1 = offs[node + 1];
  float m0 = -INFINITY, m1 = -INFINITY;
  float z0 = 0.f, z1 = 0.f, a0 = 0.f, a1 = 0.f;
  int sidx_next = (e0 < e1) ? ssrc[e0] : 0;
  for (int e = e0; e < e1; ++e) {
    int sidx = sidx_next;
    if (e + 1 < e1) sidx_next = ssrc[e + 1];  // prefetch index ahead of exp chain
    float4 w = ((const float4*)(qv + (size_t)sidx * 256))[lane];
    float t0 = w.x * kc.x, t1 = w.y * kc.y;
    float nm0 = fmaxf(m0, t0), nm1 = fmaxf(m1, t1);
    float c0 = expf(m0 - nm0), c1 = expf(m1 - nm1);
    float p0 = expf(t0 - nm0), p1 = expf(t1 - nm1);
    z0 = z0 * c0 + p0;           z1 = z1 * c1 + p1;
    a0 = a0 * c0 + p0 * w.z;     a1 = a1 * c1 + p1 * w.w;
    m0 = nm0; m1 = nm1;
  }
  float2 o;
  o.x = (e1 > e0) ? a0 / z0 : 0.f;
  o.y = (e1 > e0) ? a1 / z1 : 0.f;
  ((float2*)(rst + (size_t)node * 128))[lane] = o;
}

// ============================ split-bf16 MFMA GEMM ============================
// C[nrows, M] = A[nrows, K] @ W[K, M], operands pre-split into bf16 hi/lo.
// a*b ~= ah*bh + al*bh + ah*bl  (3 MFMAs / 16x16 tile / k-block).
// Tile 128x128, BK=32 fp32, 4 waves of 64x64, mfma_f32_16x16x32_bf16.
// ACT 0: scatter to qv/kbuf (qkv).  ACT 1: +bias, gelu -> hi/lo bf16 out.
// ACT 2: +bias +residual -> fp32 out.
template <int ACT>
__global__ __launch_bounds__(256) void gemm_split(
    const u16* __restrict__ Ah, const u16* __restrict__ Al,
    const u16* __restrict__ BhT, const u16* __restrict__ BlT,
    const float* __restrict__ bias, const float* __restrict__ res,
    float* __restrict__ outF, u16* __restrict__ outH, u16* __restrict__ outL,
    float* __restrict__ qv, float* __restrict__ kbuf,
    int nrows, int K, int M) {
  __shared__ u16 Ae[128][72];  // [m][k']: k' 0..31 hi, 32..63 lo, pad->72 (2-way max alias: free)
  __shared__ u16 Be[128][72];  // [n][k']
  int tid = threadIdx.x;
  int lane = tid & 63;
  int wid = tid >> 6;
  int wr = wid >> 1, wc = wid & 1;
  int lr = lane & 15, lg = lane >> 4;
  int row0 = blockIdx.y * 128, col0 = blockIdx.x * 128;
  bool full_tile = (row0 + 128 <= nrows);  // 390 of 391 row-blocks

  f32x4 acc[4][4] = {};

  // staging assignment: thread covers rows ra0 and ra0+64, 8 shorts at ka0
  int ra0 = tid >> 2;
  int ka0 = (tid & 3) * 8;

  for (int k0 = 0; k0 < K; k0 += 32) {
    __syncthreads();
    if (full_tile) {  // unguarded fast path
      int gr = row0 + ra0;
      *(u16x8*)&Ae[ra0][ka0]           = *(const u16x8*)(Ah + (size_t)gr * K + k0 + ka0);
      *(u16x8*)&Ae[ra0][32 + ka0]      = *(const u16x8*)(Al + (size_t)gr * K + k0 + ka0);
      *(u16x8*)&Ae[ra0 + 64][ka0]      = *(const u16x8*)(Ah + (size_t)(gr + 64) * K + k0 + ka0);
      *(u16x8*)&Ae[ra0 + 64][32 + ka0] = *(const u16x8*)(Al + (size_t)(gr + 64) * K + k0 + ka0);
    } else {
      int gr = row0 + ra0;
      u16x8 h8 = {}, l8 = {};
      if (gr < nrows) {
        h8 = *(const u16x8*)(Ah + (size_t)gr * K + k0 + ka0);
        l8 = *(const u16x8*)(Al + (size_t)gr * K + k0 + ka0);
      }
      *(u16x8*)&Ae[ra0][ka0] = h8;
      *(u16x8*)&Ae[ra0][32 + ka0] = l8;
      gr += 64;
      u16x8 h8b = {}, l8b = {};
      if (gr < nrows) {
        h8b = *(const u16x8*)(Ah + (size_t)gr * K + k0 + ka0);
        l8b = *(const u16x8*)(Al + (size_t)gr * K + k0 + ka0);
      }
      *(u16x8*)&Ae[ra0 + 64][ka0] = h8b;
      *(u16x8*)&Ae[ra0 + 64][32 + ka0] = l8b;
    }
    {  // stage B (M is a multiple of 128 -> no guard)
      int gc = col0 + ra0;
      *(u16x8*)&Be[ra0][ka0]           = *(const u16x8*)(BhT + (size_t)gc * K + k0 + ka0);
      *(u16x8*)&Be[ra0][32 + ka0]      = *(const u16x8*)(BlT + (size_t)gc * K + k0 + ka0);
      *(u16x8*)&Be[ra0 + 64][ka0]      = *(const u16x8*)(BhT + (size_t)(gc + 64) * K + k0 + ka0);
      *(u16x8*)&Be[ra0 + 64][32 + ka0] = *(const u16x8*)(BlT + (size_t)(gc + 64) * K + k0 + ka0);
    }
    __syncthreads();

    bf16x8 afh[4], afl[4], bfh[4], bfl[4];
#pragma unroll
    for (int mi = 0; mi < 4; ++mi) {
      afh[mi] = *(const bf16x8*)&Ae[wr * 64 + mi * 16 + lr][lg * 8];
      afl[mi] = *(const bf16x8*)&Ae[wr * 64 + mi * 16 + lr][32 + lg * 8];
    }
#pragma unroll
    for (int ni = 0; ni < 4; ++ni) {
      bfh[ni] = *(const bf16x8*)&Be[wc * 64 + ni * 16 + lr][lg * 8];
      bfl[ni] = *(const bf16x8*)&Be[wc * 64 + ni * 16 + lr][32 + lg * 8];
    }
#pragma unroll
    for (int mi = 0; mi < 4; ++mi)
#pragma unroll
      for (int ni = 0; ni < 4; ++ni) {
        acc[mi][ni] = __builtin_amdgcn_mfma_f32_16x16x32_bf16(afh[mi], bfh[ni], acc[mi][ni], 0, 0, 0);
        acc[mi][ni] = __builtin_amdgcn_mfma_f32_16x16x32_bf16(afl[mi], bfh[ni], acc[mi][ni], 0, 0, 0);
        acc[mi][ni] = __builtin_amdgcn_mfma_f32_16x16x32_bf16(afh[mi], bfl[ni], acc[mi][ni], 0, 0, 0);
      }
  }

  // epilogue: C/D layout col=lane&15, row=(lane>>4)*4+reg  [m89/m91]
#pragma unroll
  for (int mi = 0; mi < 4; ++mi) {
#pragma unroll
    for (int j = 0; j < 4; ++j) {
      int r = row0 + wr * 64 + mi * 16 + lg * 4 + j;
      if (!full_tile && r >= nrows) continue;
#pragma unroll
      for (int ni = 0; ni < 4; ++ni) {
        int c = col0 + wc * 64 + ni * 16 + lr;
        float v = acc[mi][ni][j];
        if (ACT == 0) {
          if (c < 128) {
            qv[(size_t)r * 256 + ((c >> 1) << 2) + (c & 1)] = v;
          } else if (c < 256) {
            kbuf[(size_t)r * 128 + (c - 128)] = v;
          } else {
            int cc = c - 256;
            qv[(size_t)r * 256 + ((cc >> 1) << 2) + 2 + (cc & 1)] = v;
          }
        } else if (ACT == 1) {
          v += bias[c];
          v = 0.5f * v * (1.0f + erff(v * 0.70710678118654752f));
          u16 hb = f2bf(v);
          outH[(size_t)r * M + c] = hb;
          outL[(size_t)r * M + c] = f2bf(v - bf2f(hb));
        } else {
          v += bias[c] + res[(size_t)r * M + c];
          outF[(size_t)r * M + c] = v;
        }
      }
    }
  }
}

// ============================ driver ============================
extern "C" void kernel_launch(void* const* d_in, const int* in_sizes, int n_in,
                              void* d_out, int out_size, void* d_ws, size_t ws_size,
                              hipStream_t stream) {
  const float* h_in   = (const float*)d_in[0];
  const int*   src    = (const int*)d_in[1];
  const int*   dst    = (const int*)d_in[2];
  const float* norm_w = (const float*)d_in[3];
  const float* norm_b = (const float*)d_in[4];
  const float* nin_w  = (const float*)d_in[5];
  const float* nin_b  = (const float*)d_in[6];
  const float* Wqkv   = (const float*)d_in[7];
  const float* no_w   = (const float*)d_in[8];
  const float* no_b   = (const float*)d_in[9];
  const float* W1     = (const float*)d_in[10];
  const float* b1     = (const float*)d_in[11];
  const float* W2     = (const float*)d_in[12];
  const float* b2     = (const float*)d_in[13];
  float* out = (float*)d_out;

  // workspace layout (~158 MB)
  char* wsp = (char*)d_ws;
  float* h_cur = (float*)wsp;             wsp += (size_t)N_NODES * 128 * 4;
  u16* s_hi = (u16*)wsp;                  wsp += (size_t)N_NODES * 128 * 2;
  u16* s_lo = (u16*)wsp;                  wsp += (size_t)N_NODES * 128 * 2;
  char* R = wsp;                          wsp += (size_t)N_NODES * 512 * 4;
  float* qv   = (float*)R;                        // [N][256]
  float* kbuf = (float*)(R + (size_t)N_NODES * 256 * 4);  // [N][128]
  u16* hid_h  = (u16*)R;                          // [N][512] (aliases qv/kbuf, disjoint in time)
  u16* hid_l  = (u16*)(R + (size_t)N_NODES * 512 * 2);
  u16* WqT_h = (u16*)wsp; wsp += 49152 * 2;
  u16* WqT_l = (u16*)wsp; wsp += 49152 * 2;
  u16* W1T_h = (u16*)wsp; wsp += 65536 * 2;
  u16* W1T_l = (u16*)wsp; wsp += 65536 * 2;
  u16* W2T_h = (u16*)wsp; wsp += 65536 * 2;
  u16* W2T_l = (u16*)wsp; wsp += 65536 * 2;
  int* cnt    = (int*)wsp;
  int* cursor = cnt + N_NODES;
  int* offs   = cursor + N_NODES;
  int* ssrc   = offs + N_NODES + 1;

  // CSR by dst (rebuilt every call)
  hipMemsetAsync(cnt, 0, N_NODES * sizeof(int), stream);
  count_kernel<<<(N_EDGES + 255) / 256, 256, 0, stream>>>(dst, cnt, N_EDGES);
  scan_kernel<<<1, 1024, 0, stream>>>(cnt, offs, cursor, N_NODES);
  scatter_kernel<<<(N_EDGES + 255) / 256, 256, 0, stream>>>(src, dst, cursor, ssrc, N_EDGES);

  // weight transpose+split (once per call; weights shared across layers)
  wsplit_kernel<<<(128 * 384 + 255) / 256, 256, 0, stream>>>(Wqkv, WqT_h, WqT_l, 128, 384);
  wsplit_kernel<<<(128 * 512 + 255) / 256, 256, 0, stream>>>(W1, W1T_h, W1T_l, 128, 512);
  wsplit_kernel<<<(512 * 128 + 255) / 256, 256, 0, stream>>>(W2, W2T_h, W2T_l, 512, 128);

  const int grid_rows = (N_NODES + 127) / 128;  // 391

  for (int layer = 0; layer < 3; ++layer) {
    const float* h_src = (layer == 0) ? h_in : h_cur;
    float* h_dst = (layer == 2) ? out : h_cur;

    // s = LN(LN(h)) -> bf16 hi/lo
    ln2_kernel<<<12500, 256, 0, stream>>>(h_src, norm_w, norm_b, nin_w, nin_b, s_hi, s_lo, N_NODES);
    // qkv = s @ Wqkv -> qv interleaved + kbuf
    gemm_split<0><<<dim3(3, grid_rows), 256, 0, stream>>>(
        s_hi, s_lo, WqT_h, WqT_l, nullptr, nullptr,
        nullptr, nullptr, nullptr, qv, kbuf, N_NODES, 128, 384);
    // per-channel edge softmax + aggregation (rst = d_out scratch)
    attn_kernel<<<12500, 256, 0, stream>>>(qv, kbuf, offs, ssrc, out, N_NODES);
    // y = LN(rst) -> bf16 hi/lo
    ln1_kernel<<<12500, 256, 0, stream>>>(out, no_w, no_b, s_hi, s_lo, N_NODES);
    // hidden = gelu(y @ W1 + b1) -> bf16 hi/lo (aliases qv/kbuf region)
    gemm_split<1><<<dim3(4, grid_rows), 256, 0, stream>>>(
        s_hi, s_lo, W1T_h, W1T_l, b1, nullptr,
        nullptr, hid_h, hid_l, nullptr, nullptr, N_NODES, 128, 512);
    // h = hidden @ W2 + b2 + h
    gemm_split<2><<<dim3(1, grid_rows), 256, 0, stream>>>(
        hid_h, hid_l, W2T_h, W2T_l, b2, h_src,
        h_dst, nullptr, nullptr, nullptr, nullptr, N_NODES, 512, 128);
  }
}

// Round 4
// 981.447 us; speedup vs baseline: 1.1994x; 1.1994x over previous
//
#include <hip/hip_runtime.h>
#include <math.h>

#define N_NODES 50000
#define N_EDGES 800000
#define EPS 1e-5f

typedef unsigned short u16;
typedef __attribute__((ext_vector_type(8))) u16 u16x8;
typedef __attribute__((ext_vector_type(8))) short bf16x8;
typedef __attribute__((ext_vector_type(4))) float f32x4;

__device__ __forceinline__ u16 f2bf(float x) {
  unsigned u = __float_as_uint(x);
  return (u16)((u + 0x7FFFu + ((u >> 16) & 1u)) >> 16);
}
__device__ __forceinline__ float bf2f(u16 b) {
  return __uint_as_float(((unsigned)b) << 16);
}

// ============================ CSR build ============================
__global__ void count_kernel(const int* __restrict__ dst, int* __restrict__ cnt, int e_total) {
  int e = blockIdx.x * 256 + threadIdx.x;
  if (e < e_total) atomicAdd(&cnt[dst[e]], 1);
}

__global__ void scan_kernel(const int* __restrict__ cnt, int* __restrict__ offs,
                            int* __restrict__ cursor, int n) {
  __shared__ int buf[1024];
  int t = threadIdx.x;
  int chunk = (n + 1023) >> 10;
  int lo = t * chunk, hi = min(lo + chunk, n);
  int s = 0;
  for (int i = lo; i < hi; ++i) s += cnt[i];
  buf[t] = s;
  __syncthreads();
  for (int st = 1; st < 1024; st <<= 1) {
    int v = (t >= st) ? buf[t - st] : 0;
    __syncthreads();
    buf[t] += v;
    __syncthreads();
  }
  int run = (t == 0) ? 0 : buf[t - 1];
  for (int i = lo; i < hi; ++i) {
    int c = cnt[i];
    offs[i] = run; cursor[i] = run;
    run += c;
  }
  if (lo < n && hi == n) offs[n] = run;
}

__global__ void scatter_kernel(const int* __restrict__ src, const int* __restrict__ dst,
                               int* __restrict__ cursor, int* __restrict__ ssrc, int e_total) {
  int e = blockIdx.x * 256 + threadIdx.x;
  if (e < e_total) {
    int p = atomicAdd(&cursor[dst[e]], 1);
    ssrc[p] = src[e];
  }
}

// ============================ weight transpose + split ============================
// W[K][M] fp32 -> WT_h/WT_l [M][K] bf16 bits
__global__ void wsplit_kernel(const float* __restrict__ W, u16* __restrict__ outH,
                              u16* __restrict__ outL, int K, int M) {
  int e = blockIdx.x * 256 + threadIdx.x;
  if (e >= K * M) return;
  int n = e % M, k = e / M;
  float a = W[e];
  u16 hb = f2bf(a);
  outH[(size_t)n * K + k] = hb;
  outL[(size_t)n * K + k] = f2bf(a - bf2f(hb));
}

// ============================ LayerNorm ============================
__device__ __forceinline__ float wave_sum(float v) {
#pragma unroll
  for (int m = 32; m > 0; m >>= 1) v += __shfl_xor(v, m, 64);
  return v;
}

// out = LN(LN(h, w1, b1), w2, b2), emitted as bf16 hi/lo split
__global__ __launch_bounds__(256) void ln2_kernel(
    const float* __restrict__ h,
    const float* __restrict__ w1, const float* __restrict__ b1,
    const float* __restrict__ w2, const float* __restrict__ b2,
    u16* __restrict__ s_hi, u16* __restrict__ s_lo, int n) {
  int lane = threadIdx.x & 63;
  int row = blockIdx.x * 4 + (threadIdx.x >> 6);
  if (row >= n) return;
  float2 v = ((const float2*)(h + (size_t)row * 128))[lane];
  float s = wave_sum(v.x + v.y);
  float q = wave_sum(v.x * v.x + v.y * v.y);
  float mean = s * (1.0f / 128.0f);
  float var = q * (1.0f / 128.0f) - mean * mean;
  float rs = 1.0f / sqrtf(var + EPS);
  float2 wv = ((const float2*)w1)[lane];
  float2 bv = ((const float2*)b1)[lane];
  float x0 = (v.x - mean) * rs * wv.x + bv.x;
  float x1 = (v.y - mean) * rs * wv.y + bv.y;
  float s2 = wave_sum(x0 + x1);
  float q2 = wave_sum(x0 * x0 + x1 * x1);
  float mean2 = s2 * (1.0f / 128.0f);
  float var2 = q2 * (1.0f / 128.0f) - mean2 * mean2;
  float rs2 = 1.0f / sqrtf(var2 + EPS);
  float2 wv2 = ((const float2*)w2)[lane];
  float2 bv2 = ((const float2*)b2)[lane];
  float o0 = (x0 - mean2) * rs2 * wv2.x + bv2.x;
  float o1 = (x1 - mean2) * rs2 * wv2.y + bv2.y;
  u16 h0 = f2bf(o0), h1 = f2bf(o1);
  u16 l0 = f2bf(o0 - bf2f(h0)), l1 = f2bf(o1 - bf2f(h1));
  ((unsigned*)s_hi)[(size_t)row * 64 + lane] = (unsigned)h0 | ((unsigned)h1 << 16);
  ((unsigned*)s_lo)[(size_t)row * 64 + lane] = (unsigned)l0 | ((unsigned)l1 << 16);
}

__global__ __launch_bounds__(256) void ln1_kernel(
    const float* __restrict__ h,
    const float* __restrict__ w1, const float* __restrict__ b1,
    u16* __restrict__ s_hi, u16* __restrict__ s_lo, int n) {
  int lane = threadIdx.x & 63;
  int row = blockIdx.x * 4 + (threadIdx.x >> 6);
  if (row >= n) return;
  float2 v = ((const float2*)(h + (size_t)row * 128))[lane];
  float s = wave_sum(v.x + v.y);
  float q = wave_sum(v.x * v.x + v.y * v.y);
  float mean = s * (1.0f / 128.0f);
  float var = q * (1.0f / 128.0f) - mean * mean;
  float rs = 1.0f / sqrtf(var + EPS);
  float2 wv = ((const float2*)w1)[lane];
  float2 bv = ((const float2*)b1)[lane];
  float o0 = (v.x - mean) * rs * wv.x + bv.x;
  float o1 = (v.y - mean) * rs * wv.y + bv.y;
  u16 h0 = f2bf(o0), h1 = f2bf(o1);
  u16 l0 = f2bf(o0 - bf2f(h0)), l1 = f2bf(o1 - bf2f(h1));
  ((unsigned*)s_hi)[(size_t)row * 64 + lane] = (unsigned)h0 | ((unsigned)h1 << 16);
  ((unsigned*)s_lo)[(size_t)row * 64 + lane] = (unsigned)l0 | ((unsigned)l1 << 16);
}

// ============================ Graph attention ============================
// One wave per dst node; lane owns channels (2l, 2l+1). qv bf16 [N][256]:
// q_c at 4*(c>>1)+(c&1), v_c at 4*(c>>1)+2+(c&1) -> one dwordx2/lane/edge.
// Scores |q_c*k_c*scale| << 1, so softmax needs NO max subtraction
// (shift-invariant; exp perfectly conditioned near 0).
__global__ __launch_bounds__(256) void attn_kernel(
    const u16* __restrict__ qv, const float* __restrict__ kbuf,
    const int* __restrict__ offs, const int* __restrict__ ssrc,
    float* __restrict__ rst, int n) {
  int lane = threadIdx.x & 63;
  int node = blockIdx.x * 4 + (threadIdx.x >> 6);
  if (node >= n) return;
  const float SCALE = 0.08838834764831845f;  // 128^-0.5
  float2 kc = ((const float2*)(kbuf + (size_t)node * 128))[lane];
  kc.x *= SCALE; kc.y *= SCALE;
  int e0 = offs[node], e1 = offs[node + 1];
  float z0 = 0.f, z1 = 0.f, a0 = 0.f, a1 = 0.f;
  int e = e0;
  for (; e + 1 < e1; e += 2) {  // 2-way unroll: two independent gathers in flight
    int s0 = ssrc[e], s1 = ssrc[e + 1];
    ushort4 wa = ((const ushort4*)(qv + (size_t)s0 * 256))[lane];
    ushort4 wb = ((const ushort4*)(qv + (size_t)s1 * 256))[lane];
    float pa0 = __expf(bf2f(wa.x) * kc.x), pa1 = __expf(bf2f(wa.y) * kc.y);
    float pb0 = __expf(bf2f(wb.x) * kc.x), pb1 = __expf(bf2f(wb.y) * kc.y);
    z0 += pa0 + pb0;
    z1 += pa1 + pb1;
    a0 = fmaf(pa0, bf2f(wa.z), fmaf(pb0, bf2f(wb.z), a0));
    a1 = fmaf(pa1, bf2f(wa.w), fmaf(pb1, bf2f(wb.w), a1));
  }
  if (e < e1) {
    int s0 = ssrc[e];
    ushort4 wa = ((const ushort4*)(qv + (size_t)s0 * 256))[lane];
    float pa0 = __expf(bf2f(wa.x) * kc.x), pa1 = __expf(bf2f(wa.y) * kc.y);
    z0 += pa0; z1 += pa1;
    a0 = fmaf(pa0, bf2f(wa.z), a0);
    a1 = fmaf(pa1, bf2f(wa.w), a1);
  }
  float2 o;
  o.x = (e1 > e0) ? a0 / z0 : 0.f;
  o.y = (e1 > e0) ? a1 / z1 : 0.f;
  ((float2*)(rst + (size_t)node * 128))[lane] = o;
}

// ============================ split-bf16 MFMA GEMM ============================
// C[nrows, M] = A[nrows, K] @ W[K, M].
// SPLITA: a*b ~= ah*bh + al*bh + ah*bl (3 MFMAs). !SPLITA: a*(bh+bl) (2 MFMAs, exact in b).
// Tile 128x128, BK=32 fp32, 4 waves of 64x64, mfma_f32_16x16x32_bf16.
// ACT 0: scatter bf16 qv + fp32 kbuf.  ACT 1: +bias, gelu -> bf16 out (hi only).
// ACT 2: +bias +residual -> fp32 out.
template <int ACT, bool SPLITA>
__global__ __launch_bounds__(256) void gemm_split(
    const u16* __restrict__ Ah, const u16* __restrict__ Al,
    const u16* __restrict__ BhT, const u16* __restrict__ BlT,
    const float* __restrict__ bias, const float* __restrict__ res,
    float* __restrict__ outF, u16* __restrict__ outH,
    u16* __restrict__ qvb, float* __restrict__ kbuf,
    int nrows, int K, int M) {
  __shared__ u16 Ae[128][72];  // [m][k']: k' 0..31 hi, 32..63 lo, pad->72 (2-way alias max: free)
  __shared__ u16 Be[128][72];  // [n][k']
  int tid = threadIdx.x;
  int lane = tid & 63;
  int wid = tid >> 6;
  int wr = wid >> 1, wc = wid & 1;
  int lr = lane & 15, lg = lane >> 4;
  int row0 = blockIdx.y * 128, col0 = blockIdx.x * 128;
  bool full_tile = (row0 + 128 <= nrows);  // 390 of 391 row-blocks

  f32x4 acc[4][4] = {};

  // staging assignment: thread covers rows ra0 and ra0+64, 8 shorts at ka0
  int ra0 = tid >> 2;
  int ka0 = (tid & 3) * 8;

  for (int k0 = 0; k0 < K; k0 += 32) {
    __syncthreads();
    if (full_tile) {  // unguarded fast path
      int gr = row0 + ra0;
      *(u16x8*)&Ae[ra0][ka0]      = *(const u16x8*)(Ah + (size_t)gr * K + k0 + ka0);
      *(u16x8*)&Ae[ra0 + 64][ka0] = *(const u16x8*)(Ah + (size_t)(gr + 64) * K + k0 + ka0);
      if (SPLITA) {
        *(u16x8*)&Ae[ra0][32 + ka0]      = *(const u16x8*)(Al + (size_t)gr * K + k0 + ka0);
        *(u16x8*)&Ae[ra0 + 64][32 + ka0] = *(const u16x8*)(Al + (size_t)(gr + 64) * K + k0 + ka0);
      }
    } else {
      int gr = row0 + ra0;
      u16x8 h8 = {}, l8 = {};
      if (gr < nrows) {
        h8 = *(const u16x8*)(Ah + (size_t)gr * K + k0 + ka0);
        if (SPLITA) l8 = *(const u16x8*)(Al + (size_t)gr * K + k0 + ka0);
      }
      *(u16x8*)&Ae[ra0][ka0] = h8;
      if (SPLITA) *(u16x8*)&Ae[ra0][32 + ka0] = l8;
      gr += 64;
      u16x8 h8b = {}, l8b = {};
      if (gr < nrows) {
        h8b = *(const u16x8*)(Ah + (size_t)gr * K + k0 + ka0);
        if (SPLITA) l8b = *(const u16x8*)(Al + (size_t)gr * K + k0 + ka0);
      }
      *(u16x8*)&Ae[ra0 + 64][ka0] = h8b;
      if (SPLITA) *(u16x8*)&Ae[ra0 + 64][32 + ka0] = l8b;
    }
    {  // stage B (M is a multiple of 128 -> no guard)
      int gc = col0 + ra0;
      *(u16x8*)&Be[ra0][ka0]           = *(const u16x8*)(BhT + (size_t)gc * K + k0 + ka0);
      *(u16x8*)&Be[ra0][32 + ka0]      = *(const u16x8*)(BlT + (size_t)gc * K + k0 + ka0);
      *(u16x8*)&Be[ra0 + 64][ka0]      = *(const u16x8*)(BhT + (size_t)(gc + 64) * K + k0 + ka0);
      *(u16x8*)&Be[ra0 + 64][32 + ka0] = *(const u16x8*)(BlT + (size_t)(gc + 64) * K + k0 + ka0);
    }
    __syncthreads();

    bf16x8 afh[4], afl[4], bfh[4], bfl[4];
#pragma unroll
    for (int mi = 0; mi < 4; ++mi) {
      afh[mi] = *(const bf16x8*)&Ae[wr * 64 + mi * 16 + lr][lg * 8];
      if (SPLITA) afl[mi] = *(const bf16x8*)&Ae[wr * 64 + mi * 16 + lr][32 + lg * 8];
    }
#pragma unroll
    for (int ni = 0; ni < 4; ++ni) {
      bfh[ni] = *(const bf16x8*)&Be[wc * 64 + ni * 16 + lr][lg * 8];
      bfl[ni] = *(const bf16x8*)&Be[wc * 64 + ni * 16 + lr][32 + lg * 8];
    }
#pragma unroll
    for (int mi = 0; mi < 4; ++mi)
#pragma unroll
      for (int ni = 0; ni < 4; ++ni) {
        acc[mi][ni] = __builtin_amdgcn_mfma_f32_16x16x32_bf16(afh[mi], bfh[ni], acc[mi][ni], 0, 0, 0);
        if (SPLITA)
          acc[mi][ni] = __builtin_amdgcn_mfma_f32_16x16x32_bf16(afl[mi], bfh[ni], acc[mi][ni], 0, 0, 0);
        acc[mi][ni] = __builtin_amdgcn_mfma_f32_16x16x32_bf16(afh[mi], bfl[ni], acc[mi][ni], 0, 0, 0);
      }
  }

  // epilogue: C/D layout col=lane&15, row=(lane>>4)*4+reg  [m89/m91]
#pragma unroll
  for (int mi = 0; mi < 4; ++mi) {
#pragma unroll
    for (int j = 0; j < 4; ++j) {
      int r = row0 + wr * 64 + mi * 16 + lg * 4 + j;
      if (!full_tile && r >= nrows) continue;
#pragma unroll
      for (int ni = 0; ni < 4; ++ni) {
        int c = col0 + wc * 64 + ni * 16 + lr;
        float v = acc[mi][ni][j];
        if (ACT == 0) {
          if (c < 128) {
            qvb[(size_t)r * 256 + ((c >> 1) << 2) + (c & 1)] = f2bf(v);
          } else if (c < 256) {
            kbuf[(size_t)r * 128 + (c - 128)] = v;
          } else {
            int cc = c - 256;
            qvb[(size_t)r * 256 + ((cc >> 1) << 2) + 2 + (cc & 1)] = f2bf(v);
          }
        } else if (ACT == 1) {
          v += bias[c];
          v = 0.5f * v * (1.0f + erff(v * 0.70710678118654752f));
          outH[(size_t)r * M + c] = f2bf(v);
        } else {
          v += bias[c] + res[(size_t)r * M + c];
          outF[(size_t)r * M + c] = v;
        }
      }
    }
  }
}

// ============================ driver ============================
extern "C" void kernel_launch(void* const* d_in, const int* in_sizes, int n_in,
                              void* d_out, int out_size, void* d_ws, size_t ws_size,
                              hipStream_t stream) {
  const float* h_in   = (const float*)d_in[0];
  const int*   src    = (const int*)d_in[1];
  const int*   dst    = (const int*)d_in[2];
  const float* norm_w = (const float*)d_in[3];
  const float* norm_b = (const float*)d_in[4];
  const float* nin_w  = (const float*)d_in[5];
  const float* nin_b  = (const float*)d_in[6];
  const float* Wqkv   = (const float*)d_in[7];
  const float* no_w   = (const float*)d_in[8];
  const float* no_b   = (const float*)d_in[9];
  const float* W1     = (const float*)d_in[10];
  const float* b1     = (const float*)d_in[11];
  const float* W2     = (const float*)d_in[12];
  const float* b2     = (const float*)d_in[13];
  float* out = (float*)d_out;

  // workspace layout (~130 MB)
  char* wsp = (char*)d_ws;
  float* h_cur = (float*)wsp;             wsp += (size_t)N_NODES * 128 * 4;
  u16* s_hi = (u16*)wsp;                  wsp += (size_t)N_NODES * 128 * 2;
  u16* s_lo = (u16*)wsp;                  wsp += (size_t)N_NODES * 128 * 2;
  u16* qvb  = (u16*)wsp;                  wsp += (size_t)N_NODES * 256 * 2;  // bf16 q|v interleaved
  float* kbuf = (float*)wsp;              wsp += (size_t)N_NODES * 128 * 4;
  u16* hid  = (u16*)wsp;                  wsp += (size_t)N_NODES * 512 * 2;  // bf16 hidden
  u16* WqT_h = (u16*)wsp; wsp += 49152 * 2;
  u16* WqT_l = (u16*)wsp; wsp += 49152 * 2;
  u16* W1T_h = (u16*)wsp; wsp += 65536 * 2;
  u16* W1T_l = (u16*)wsp; wsp += 65536 * 2;
  u16* W2T_h = (u16*)wsp; wsp += 65536 * 2;
  u16* W2T_l = (u16*)wsp; wsp += 65536 * 2;
  int* cnt    = (int*)wsp;
  int* cursor = cnt + N_NODES;
  int* offs   = cursor + N_NODES;
  int* ssrc   = offs + N_NODES + 1;

  // CSR by dst (rebuilt every call)
  hipMemsetAsync(cnt, 0, N_NODES * sizeof(int), stream);
  count_kernel<<<(N_EDGES + 255) / 256, 256, 0, stream>>>(dst, cnt, N_EDGES);
  scan_kernel<<<1, 1024, 0, stream>>>(cnt, offs, cursor, N_NODES);
  scatter_kernel<<<(N_EDGES + 255) / 256, 256, 0, stream>>>(src, dst, cursor, ssrc, N_EDGES);

  // weight transpose+split (once per call; weights shared across layers)
  wsplit_kernel<<<(128 * 384 + 255) / 256, 256, 0, stream>>>(Wqkv, WqT_h, WqT_l, 128, 384);
  wsplit_kernel<<<(128 * 512 + 255) / 256, 256, 0, stream>>>(W1, W1T_h, W1T_l, 128, 512);
  wsplit_kernel<<<(512 * 128 + 255) / 256, 256, 0, stream>>>(W2, W2T_h, W2T_l, 512, 128);

  const int grid_rows = (N_NODES + 127) / 128;  // 391

  for (int layer = 0; layer < 3; ++layer) {
    const float* h_src = (layer == 0) ? h_in : h_cur;
    float* h_dst = (layer == 2) ? out : h_cur;

    // s = LN(LN(h)) -> bf16 hi/lo
    ln2_kernel<<<12500, 256, 0, stream>>>(h_src, norm_w, norm_b, nin_w, nin_b, s_hi, s_lo, N_NODES);
    // qkv = s @ Wqkv -> bf16 qv interleaved + fp32 kbuf
    gemm_split<0, true><<<dim3(3, grid_rows), 256, 0, stream>>>(
        s_hi, s_lo, WqT_h, WqT_l, nullptr, nullptr,
        nullptr, nullptr, qvb, kbuf, N_NODES, 128, 384);
    // per-channel edge softmax + aggregation (rst = d_out scratch)
    attn_kernel<<<12500, 256, 0, stream>>>(qvb, kbuf, offs, ssrc, out, N_NODES);
    // y = LN(rst) -> bf16 hi/lo
    ln1_kernel<<<12500, 256, 0, stream>>>(out, no_w, no_b, s_hi, s_lo, N_NODES);
    // hidden = gelu(y @ W1 + b1) -> bf16
    gemm_split<1, true><<<dim3(4, grid_rows), 256, 0, stream>>>(
        s_hi, s_lo, W1T_h, W1T_l, b1, nullptr,
        nullptr, hid, nullptr, nullptr, N_NODES, 128, 512);
    // h = hidden @ W2 + b2 + h  (A unsplit: 2 MFMAs, b still 22-bit)
    gemm_split<2, false><<<dim3(1, grid_rows), 256, 0, stream>>>(
        hid, nullptr, W2T_h, W2T_l, b2, h_src,
        h_dst, nullptr, nullptr, nullptr, N_NODES, 512, 128);
  }
}

// Round 5
// 861.741 us; speedup vs baseline: 1.3660x; 1.1389x over previous
//
#include <hip/hip_runtime.h>
#include <math.h>

#define N_NODES 50000
#define N_EDGES 800000
#define EPS 1e-5f

#define SCAN_CHUNK 1024
#define SCAN_NBLK ((N_NODES + SCAN_CHUNK - 1) / SCAN_CHUNK)  // 49

typedef unsigned short u16;
typedef __attribute__((ext_vector_type(8))) u16 u16x8;
typedef __attribute__((ext_vector_type(8))) short bf16x8;
typedef __attribute__((ext_vector_type(4))) float f32x4;

__device__ __forceinline__ u16 f2bf(float x) {
  unsigned u = __float_as_uint(x);
  return (u16)((u + 0x7FFFu + ((u >> 16) & 1u)) >> 16);
}
__device__ __forceinline__ float bf2f(u16 b) {
  return __uint_as_float(((unsigned)b) << 16);
}

// ============================ CSR build ============================
__global__ void count_kernel(const int* __restrict__ dst, int* __restrict__ cnt, int e_total) {
  int e = blockIdx.x * 256 + threadIdx.x;
  if (e < e_total) atomicAdd(&cnt[dst[e]], 1);
}

// hierarchical exclusive scan: s1 (block-local) -> s2 (block sums) -> s3 (apply)
__global__ __launch_bounds__(256) void scan1_kernel(const int* __restrict__ cnt,
                                                    int* __restrict__ offs,
                                                    int* __restrict__ bsum, int n) {
  __shared__ int buf[256];
  int t = threadIdx.x;
  int base = blockIdx.x * SCAN_CHUNK + t * 4;
  int v0 = (base + 0 < n) ? cnt[base + 0] : 0;
  int v1 = (base + 1 < n) ? cnt[base + 1] : 0;
  int v2 = (base + 2 < n) ? cnt[base + 2] : 0;
  int v3 = (base + 3 < n) ? cnt[base + 3] : 0;
  int tsum = v0 + v1 + v2 + v3;
  buf[t] = tsum;
  __syncthreads();
  for (int st = 1; st < 256; st <<= 1) {
    int x = (t >= st) ? buf[t - st] : 0;
    __syncthreads();
    buf[t] += x;
    __syncthreads();
  }
  int texcl = buf[t] - tsum;  // exclusive within chunk
  if (base + 0 < n) offs[base + 0] = texcl;
  if (base + 1 < n) offs[base + 1] = texcl + v0;
  if (base + 2 < n) offs[base + 2] = texcl + v0 + v1;
  if (base + 3 < n) offs[base + 3] = texcl + v0 + v1 + v2;
  if (t == 255) bsum[blockIdx.x] = buf[255];
}

__global__ void scan2_kernel(const int* __restrict__ bsum, int* __restrict__ bbase) {
  int lane = threadIdx.x;  // 64 threads, one wave
  int v = (lane < SCAN_NBLK) ? bsum[lane] : 0;
  int orig = v;
#pragma unroll
  for (int ofs = 1; ofs < 64; ofs <<= 1) {
    int u = __shfl_up(v, ofs, 64);
    if (lane >= ofs) v += u;
  }
  if (lane < SCAN_NBLK) bbase[lane] = v - orig;
}

__global__ __launch_bounds__(256) void scan3_kernel(int* __restrict__ offs,
                                                    int* __restrict__ cursor,
                                                    const int* __restrict__ bbase, int n) {
  int t = threadIdx.x;
  int b = bbase[blockIdx.x];
  int base = blockIdx.x * SCAN_CHUNK + t * 4;
#pragma unroll
  for (int j = 0; j < 4; ++j) {
    int i = base + j;
    if (i < n) {
      int o = offs[i] + b;
      offs[i] = o;
      cursor[i] = o;
    }
  }
  if (blockIdx.x == 0 && t == 0) offs[n] = N_EDGES;
}

__global__ void scatter_kernel(const int* __restrict__ src, const int* __restrict__ dst,
                               int* __restrict__ cursor, int* __restrict__ ssrc, int e_total) {
  int e = blockIdx.x * 256 + threadIdx.x;
  if (e < e_total) {
    int p = atomicAdd(&cursor[dst[e]], 1);
    ssrc[p] = src[e];
  }
}

// ============================ weight transpose + split ============================
__global__ void wsplit_kernel(const float* __restrict__ W, u16* __restrict__ outH,
                              u16* __restrict__ outL, int K, int M) {
  int e = blockIdx.x * 256 + threadIdx.x;
  if (e >= K * M) return;
  int n = e % M, k = e / M;
  float a = W[e];
  u16 hb = f2bf(a);
  outH[(size_t)n * K + k] = hb;
  outL[(size_t)n * K + k] = f2bf(a - bf2f(hb));
}

// ============================ LayerNorm ============================
__device__ __forceinline__ float wave_sum(float v) {
#pragma unroll
  for (int m = 32; m > 0; m >>= 1) v += __shfl_xor(v, m, 64);
  return v;
}

__global__ __launch_bounds__(256) void ln2_kernel(
    const float* __restrict__ h,
    const float* __restrict__ w1, const float* __restrict__ b1,
    const float* __restrict__ w2, const float* __restrict__ b2,
    u16* __restrict__ s_hi, u16* __restrict__ s_lo, int n) {
  int lane = threadIdx.x & 63;
  int row = blockIdx.x * 4 + (threadIdx.x >> 6);
  if (row >= n) return;
  float2 v = ((const float2*)(h + (size_t)row * 128))[lane];
  float s = wave_sum(v.x + v.y);
  float q = wave_sum(v.x * v.x + v.y * v.y);
  float mean = s * (1.0f / 128.0f);
  float var = q * (1.0f / 128.0f) - mean * mean;
  float rs = 1.0f / sqrtf(var + EPS);
  float2 wv = ((const float2*)w1)[lane];
  float2 bv = ((const float2*)b1)[lane];
  float x0 = (v.x - mean) * rs * wv.x + bv.x;
  float x1 = (v.y - mean) * rs * wv.y + bv.y;
  float s2 = wave_sum(x0 + x1);
  float q2 = wave_sum(x0 * x0 + x1 * x1);
  float mean2 = s2 * (1.0f / 128.0f);
  float var2 = q2 * (1.0f / 128.0f) - mean2 * mean2;
  float rs2 = 1.0f / sqrtf(var2 + EPS);
  float2 wv2 = ((const float2*)w2)[lane];
  float2 bv2 = ((const float2*)b2)[lane];
  float o0 = (x0 - mean2) * rs2 * wv2.x + bv2.x;
  float o1 = (x1 - mean2) * rs2 * wv2.y + bv2.y;
  u16 h0 = f2bf(o0), h1 = f2bf(o1);
  u16 l0 = f2bf(o0 - bf2f(h0)), l1 = f2bf(o1 - bf2f(h1));
  ((unsigned*)s_hi)[(size_t)row * 64 + lane] = (unsigned)h0 | ((unsigned)h1 << 16);
  ((unsigned*)s_lo)[(size_t)row * 64 + lane] = (unsigned)l0 | ((unsigned)l1 << 16);
}

__global__ __launch_bounds__(256) void ln1_kernel(
    const float* __restrict__ h,
    const float* __restrict__ w1, const float* __restrict__ b1,
    u16* __restrict__ s_hi, u16* __restrict__ s_lo, int n) {
  int lane = threadIdx.x & 63;
  int row = blockIdx.x * 4 + (threadIdx.x >> 6);
  if (row >= n) return;
  float2 v = ((const float2*)(h + (size_t)row * 128))[lane];
  float s = wave_sum(v.x + v.y);
  float q = wave_sum(v.x * v.x + v.y * v.y);
  float mean = s * (1.0f / 128.0f);
  float var = q * (1.0f / 128.0f) - mean * mean;
  float rs = 1.0f / sqrtf(var + EPS);
  float2 wv = ((const float2*)w1)[lane];
  float2 bv = ((const float2*)b1)[lane];
  float o0 = (v.x - mean) * rs * wv.x + bv.x;
  float o1 = (v.y - mean) * rs * wv.y + bv.y;
  u16 h0 = f2bf(o0), h1 = f2bf(o1);
  u16 l0 = f2bf(o0 - bf2f(h0)), l1 = f2bf(o1 - bf2f(h1));
  ((unsigned*)s_hi)[(size_t)row * 64 + lane] = (unsigned)h0 | ((unsigned)h1 << 16);
  ((unsigned*)s_lo)[(size_t)row * 64 + lane] = (unsigned)l0 | ((unsigned)l1 << 16);
}

// ============================ Graph attention ============================
// No max-subtraction needed: |q_c*k_c*scale| << 1 (softmax shift-invariant).
__global__ __launch_bounds__(256) void attn_kernel(
    const u16* __restrict__ qv, const float* __restrict__ kbuf,
    const int* __restrict__ offs, const int* __restrict__ ssrc,
    float* __restrict__ rst, int n) {
  int lane = threadIdx.x & 63;
  int node = blockIdx.x * 4 + (threadIdx.x >> 6);
  if (node >= n) return;
  const float SCALE = 0.08838834764831845f;  // 128^-0.5
  float2 kc = ((const float2*)(kbuf + (size_t)node * 128))[lane];
  kc.x *= SCALE; kc.y *= SCALE;
  int e0 = offs[node], e1 = offs[node + 1];
  float z0 = 0.f, z1 = 0.f, a0 = 0.f, a1 = 0.f;
  int e = e0;
  for (; e + 1 < e1; e += 2) {
    int s0 = ssrc[e], s1 = ssrc[e + 1];
    ushort4 wa = ((const ushort4*)(qv + (size_t)s0 * 256))[lane];
    ushort4 wb = ((const ushort4*)(qv + (size_t)s1 * 256))[lane];
    float pa0 = __expf(bf2f(wa.x) * kc.x), pa1 = __expf(bf2f(wa.y) * kc.y);
    float pb0 = __expf(bf2f(wb.x) * kc.x), pb1 = __expf(bf2f(wb.y) * kc.y);
    z0 += pa0 + pb0;
    z1 += pa1 + pb1;
    a0 = fmaf(pa0, bf2f(wa.z), fmaf(pb0, bf2f(wb.z), a0));
    a1 = fmaf(pa1, bf2f(wa.w), fmaf(pb1, bf2f(wb.w), a1));
  }
  if (e < e1) {
    int s0 = ssrc[e];
    ushort4 wa = ((const ushort4*)(qv + (size_t)s0 * 256))[lane];
    float pa0 = __expf(bf2f(wa.x) * kc.x), pa1 = __expf(bf2f(wa.y) * kc.y);
    z0 += pa0; z1 += pa1;
    a0 = fmaf(pa0, bf2f(wa.z), a0);
    a1 = fmaf(pa1, bf2f(wa.w), a1);
  }
  float2 o;
  o.x = (e1 > e0) ? a0 / z0 : 0.f;
  o.y = (e1 > e0) ? a1 / z1 : 0.f;
  ((float2*)(rst + (size_t)node * 128))[lane] = o;
}

// ============================ split-bf16 MFMA GEMM (2-phase pipelined) ============================
// C[nrows, M] = A[nrows, K] @ W[K, M].
// SPLITA: a*b ~= ah*bh + al*bh + ah*bl (3 MFMAs). !SPLITA: a*(bh+bl) (2 MFMAs).
// Tile 128x128, BK=32 fp32, 4 waves of 64x64, double-buffered LDS, K templated:
// issue next tile's global loads BEFORE computing current (T3-minimum),
// one barrier per k-step.
struct StageA { u16x8 a0h, a1h, a0l, a1l; };
struct StageB { u16x8 b0h, b0l, b1h, b1l; };

template <int ACT, bool SPLITA, int K>
__global__ __launch_bounds__(256) void gemm_split(
    const u16* __restrict__ Ah, const u16* __restrict__ Al,
    const u16* __restrict__ BhT, const u16* __restrict__ BlT,
    const float* __restrict__ bias, const float* __restrict__ res,
    float* __restrict__ outF, u16* __restrict__ outH,
    u16* __restrict__ qvb, float* __restrict__ kbuf,
    int nrows, int M) {
  __shared__ u16 Ae[2][128][72];  // [buf][m][k']: k' 0..31 hi, 32..63 lo, pad->72
  __shared__ u16 Be[2][128][72];
  int tid = threadIdx.x;
  int lane = tid & 63;
  int wid = tid >> 6;
  int wr = wid >> 1, wc = wid & 1;
  int lr = lane & 15, lg = lane >> 4;
  int row0 = blockIdx.y * 128, col0 = blockIdx.x * 128;
  bool full_tile = (row0 + 128 <= nrows);

  f32x4 acc[4][4] = {};

  int ra0 = tid >> 2;
  int ka0 = (tid & 3) * 8;

  const int NT = K / 32;

  // ---- load helpers (global -> regs) ----
  auto loadA = [&](int k0, StageA& r) {
    if (full_tile) {
      int gr = row0 + ra0;
      r.a0h = *(const u16x8*)(Ah + (size_t)gr * K + k0 + ka0);
      r.a1h = *(const u16x8*)(Ah + (size_t)(gr + 64) * K + k0 + ka0);
      if (SPLITA) {
        r.a0l = *(const u16x8*)(Al + (size_t)gr * K + k0 + ka0);
        r.a1l = *(const u16x8*)(Al + (size_t)(gr + 64) * K + k0 + ka0);
      }
    } else {
      int gr = row0 + ra0;
      r.a0h = (u16x8){}; r.a1h = (u16x8){}; r.a0l = (u16x8){}; r.a1l = (u16x8){};
      if (gr < nrows) {
        r.a0h = *(const u16x8*)(Ah + (size_t)gr * K + k0 + ka0);
        if (SPLITA) r.a0l = *(const u16x8*)(Al + (size_t)gr * K + k0 + ka0);
      }
      if (gr + 64 < nrows) {
        r.a1h = *(const u16x8*)(Ah + (size_t)(gr + 64) * K + k0 + ka0);
        if (SPLITA) r.a1l = *(const u16x8*)(Al + (size_t)(gr + 64) * K + k0 + ka0);
      }
    }
  };
  auto loadB = [&](int k0, StageB& r) {
    int gc = col0 + ra0;
    r.b0h = *(const u16x8*)(BhT + (size_t)gc * K + k0 + ka0);
    r.b0l = *(const u16x8*)(BlT + (size_t)gc * K + k0 + ka0);
    r.b1h = *(const u16x8*)(BhT + (size_t)(gc + 64) * K + k0 + ka0);
    r.b1l = *(const u16x8*)(BlT + (size_t)(gc + 64) * K + k0 + ka0);
  };
  auto writeLDS = [&](int buf, const StageA& a, const StageB& b) {
    *(u16x8*)&Ae[buf][ra0][ka0] = a.a0h;
    *(u16x8*)&Ae[buf][ra0 + 64][ka0] = a.a1h;
    if (SPLITA) {
      *(u16x8*)&Ae[buf][ra0][32 + ka0] = a.a0l;
      *(u16x8*)&Ae[buf][ra0 + 64][32 + ka0] = a.a1l;
    }
    *(u16x8*)&Be[buf][ra0][ka0] = b.b0h;
    *(u16x8*)&Be[buf][ra0][32 + ka0] = b.b0l;
    *(u16x8*)&Be[buf][ra0 + 64][ka0] = b.b1h;
    *(u16x8*)&Be[buf][ra0 + 64][32 + ka0] = b.b1l;
  };

  // ---- prologue: stage tile 0 ----
  StageA ar; StageB br;
  loadA(0, ar); loadB(0, br);
  writeLDS(0, ar, br);
  __syncthreads();

#pragma unroll
  for (int t = 0; t < NT; ++t) {
    int cur = t & 1;
    // issue next tile's global loads first (latency hides under compute)
    if (t + 1 < NT) {
      loadA((t + 1) * 32, ar);
      loadB((t + 1) * 32, br);
    }
    // compute current from LDS
    bf16x8 afh[4], afl[4], bfh[4], bfl[4];
#pragma unroll
    for (int mi = 0; mi < 4; ++mi) {
      afh[mi] = *(const bf16x8*)&Ae[cur][wr * 64 + mi * 16 + lr][lg * 8];
      if (SPLITA) afl[mi] = *(const bf16x8*)&Ae[cur][wr * 64 + mi * 16 + lr][32 + lg * 8];
    }
#pragma unroll
    for (int ni = 0; ni < 4; ++ni) {
      bfh[ni] = *(const bf16x8*)&Be[cur][wc * 64 + ni * 16 + lr][lg * 8];
      bfl[ni] = *(const bf16x8*)&Be[cur][wc * 64 + ni * 16 + lr][32 + lg * 8];
    }
#pragma unroll
    for (int mi = 0; mi < 4; ++mi)
#pragma unroll
      for (int ni = 0; ni < 4; ++ni) {
        acc[mi][ni] = __builtin_amdgcn_mfma_f32_16x16x32_bf16(afh[mi], bfh[ni], acc[mi][ni], 0, 0, 0);
        if (SPLITA)
          acc[mi][ni] = __builtin_amdgcn_mfma_f32_16x16x32_bf16(afl[mi], bfh[ni], acc[mi][ni], 0, 0, 0);
        acc[mi][ni] = __builtin_amdgcn_mfma_f32_16x16x32_bf16(afh[mi], bfl[ni], acc[mi][ni], 0, 0, 0);
      }
    // write next tile to the other buffer; single barrier per k-step
    if (t + 1 < NT) writeLDS(cur ^ 1, ar, br);
    __syncthreads();
  }

  // epilogue: C/D layout col=lane&15, row=(lane>>4)*4+reg  [m89/m91]
#pragma unroll
  for (int mi = 0; mi < 4; ++mi) {
#pragma unroll
    for (int j = 0; j < 4; ++j) {
      int r = row0 + wr * 64 + mi * 16 + lg * 4 + j;
      if (!full_tile && r >= nrows) continue;
#pragma unroll
      for (int ni = 0; ni < 4; ++ni) {
        int c = col0 + wc * 64 + ni * 16 + lr;
        float v = acc[mi][ni][j];
        if (ACT == 0) {
          if (c < 128) {
            qvb[(size_t)r * 256 + ((c >> 1) << 2) + (c & 1)] = f2bf(v);
          } else if (c < 256) {
            kbuf[(size_t)r * 128 + (c - 128)] = v;
          } else {
            int cc = c - 256;
            qvb[(size_t)r * 256 + ((cc >> 1) << 2) + 2 + (cc & 1)] = f2bf(v);
          }
        } else if (ACT == 1) {
          v += bias[c];
          v = 0.5f * v * (1.0f + erff(v * 0.70710678118654752f));
          outH[(size_t)r * M + c] = f2bf(v);
        } else {
          v += bias[c] + res[(size_t)r * M + c];
          outF[(size_t)r * M + c] = v;
        }
      }
    }
  }
}

// ============================ driver ============================
extern "C" void kernel_launch(void* const* d_in, const int* in_sizes, int n_in,
                              void* d_out, int out_size, void* d_ws, size_t ws_size,
                              hipStream_t stream) {
  const float* h_in   = (const float*)d_in[0];
  const int*   src    = (const int*)d_in[1];
  const int*   dst    = (const int*)d_in[2];
  const float* norm_w = (const float*)d_in[3];
  const float* norm_b = (const float*)d_in[4];
  const float* nin_w  = (const float*)d_in[5];
  const float* nin_b  = (const float*)d_in[6];
  const float* Wqkv   = (const float*)d_in[7];
  const float* no_w   = (const float*)d_in[8];
  const float* no_b   = (const float*)d_in[9];
  const float* W1     = (const float*)d_in[10];
  const float* b1     = (const float*)d_in[11];
  const float* W2     = (const float*)d_in[12];
  const float* b2     = (const float*)d_in[13];
  float* out = (float*)d_out;

  // workspace layout (~130 MB)
  char* wsp = (char*)d_ws;
  float* h_cur = (float*)wsp;             wsp += (size_t)N_NODES * 128 * 4;
  u16* s_hi = (u16*)wsp;                  wsp += (size_t)N_NODES * 128 * 2;
  u16* s_lo = (u16*)wsp;                  wsp += (size_t)N_NODES * 128 * 2;
  u16* qvb  = (u16*)wsp;                  wsp += (size_t)N_NODES * 256 * 2;  // bf16 q|v interleaved
  float* kbuf = (float*)wsp;              wsp += (size_t)N_NODES * 128 * 4;
  u16* hid  = (u16*)wsp;                  wsp += (size_t)N_NODES * 512 * 2;  // bf16 hidden
  u16* WqT_h = (u16*)wsp; wsp += 49152 * 2;
  u16* WqT_l = (u16*)wsp; wsp += 49152 * 2;
  u16* W1T_h = (u16*)wsp; wsp += 65536 * 2;
  u16* W1T_l = (u16*)wsp; wsp += 65536 * 2;
  u16* W2T_h = (u16*)wsp; wsp += 65536 * 2;
  u16* W2T_l = (u16*)wsp; wsp += 65536 * 2;
  int* cnt    = (int*)wsp;
  int* cursor = cnt + N_NODES;
  int* offs   = cursor + N_NODES;
  int* ssrc   = offs + N_NODES + 1;
  int* bsum   = ssrc + N_EDGES;
  int* bbase  = bsum + 64;

  // CSR by dst (rebuilt every call)
  hipMemsetAsync(cnt, 0, N_NODES * sizeof(int), stream);
  count_kernel<<<(N_EDGES + 255) / 256, 256, 0, stream>>>(dst, cnt, N_EDGES);
  scan1_kernel<<<SCAN_NBLK, 256, 0, stream>>>(cnt, offs, bsum, N_NODES);
  scan2_kernel<<<1, 64, 0, stream>>>(bsum, bbase);
  scan3_kernel<<<SCAN_NBLK, 256, 0, stream>>>(offs, cursor, bbase, N_NODES);
  scatter_kernel<<<(N_EDGES + 255) / 256, 256, 0, stream>>>(src, dst, cursor, ssrc, N_EDGES);

  // weight transpose+split (once per call; weights shared across layers)
  wsplit_kernel<<<(128 * 384 + 255) / 256, 256, 0, stream>>>(Wqkv, WqT_h, WqT_l, 128, 384);
  wsplit_kernel<<<(128 * 512 + 255) / 256, 256, 0, stream>>>(W1, W1T_h, W1T_l, 128, 512);
  wsplit_kernel<<<(512 * 128 + 255) / 256, 256, 0, stream>>>(W2, W2T_h, W2T_l, 512, 128);

  const int grid_rows = (N_NODES + 127) / 128;  // 391

  for (int layer = 0; layer < 3; ++layer) {
    const float* h_src = (layer == 0) ? h_in : h_cur;
    float* h_dst = (layer == 2) ? out : h_cur;

    // s = LN(LN(h)) -> bf16 hi/lo
    ln2_kernel<<<12500, 256, 0, stream>>>(h_src, norm_w, norm_b, nin_w, nin_b, s_hi, s_lo, N_NODES);
    // qkv = s @ Wqkv -> bf16 qv interleaved + fp32 kbuf
    gemm_split<0, true, 128><<<dim3(3, grid_rows), 256, 0, stream>>>(
        s_hi, s_lo, WqT_h, WqT_l, nullptr, nullptr,
        nullptr, nullptr, qvb, kbuf, N_NODES, 384);
    // per-channel edge softmax + aggregation (rst = d_out scratch)
    attn_kernel<<<12500, 256, 0, stream>>>(qvb, kbuf, offs, ssrc, out, N_NODES);
    // y = LN(rst) -> bf16 hi/lo
    ln1_kernel<<<12500, 256, 0, stream>>>(out, no_w, no_b, s_hi, s_lo, N_NODES);
    // hidden = gelu(y @ W1 + b1) -> bf16
    gemm_split<1, true, 128><<<dim3(4, grid_rows), 256, 0, stream>>>(
        s_hi, s_lo, W1T_h, W1T_l, b1, nullptr,
        nullptr, hid, nullptr, nullptr, N_NODES, 512);
    // h = hidden @ W2 + b2 + h  (A unsplit: 2 MFMAs, b still 22-bit)
    gemm_split<2, false, 512><<<dim3(1, grid_rows), 256, 0, stream>>>(
        hid, nullptr, W2T_h, W2T_l, b2, h_src,
        h_dst, nullptr, nullptr, nullptr, N_NODES, 128);
  }
}